// Round 2
// baseline (309.990 us; speedup 1.0000x reference)
//
#include <hip/hip_runtime.h>
#include <stdint.h>

typedef __attribute__((ext_vector_type(8))) short bf16x8;   // 8 bf16 = 4 VGPR (MFMA A/B frag)
typedef __attribute__((ext_vector_type(4))) float f32x4;    // MFMA C/D frag
typedef __attribute__((ext_vector_type(4))) unsigned short us4;
typedef __attribute__((ext_vector_type(8))) unsigned short us8;

__device__ __forceinline__ unsigned short f2bf(float f) {   // RNE f32 -> bf16
  union { float f; unsigned u; } x; x.f = f;
  unsigned r = x.u + 0x7FFFu + ((x.u >> 16) & 1u);
  return (unsigned short)(r >> 16);
}
__device__ __forceinline__ float bf2f(unsigned short h) {
  union { unsigned u; float f; } x; x.u = ((unsigned)h) << 16;
  return x.f;
}

// async global->LDS, 16B per lane; LDS dest is wave-uniform base + lane*16
#define GL2LDS(g, l) __builtin_amdgcn_global_load_lds( \
    (const __attribute__((address_space(1))) unsigned int*)(g), \
    (__attribute__((address_space(3))) unsigned int*)(l), 16, 0, 0)

// raw barrier with compiler memory fence (no vmcnt/lgkm drain at runtime)
#define BARRIER() do { asm volatile("" ::: "memory"); \
  __builtin_amdgcn_s_barrier(); asm volatile("" ::: "memory"); } while (0)
#define SCHED0() __builtin_amdgcn_sched_barrier(0)

// ---------------- fused prep (unchanged) ----------------
__global__ __launch_bounds__(256)
void prep(const float* __restrict__ x,
          const float* __restrict__ wq, const float* __restrict__ wk,
          const float* __restrict__ wv, const float* __restrict__ wo,
          unsigned short* __restrict__ xb,
          unsigned short* __restrict__ wqb, unsigned short* __restrict__ wkb,
          unsigned short* __restrict__ vtb, unsigned short* __restrict__ opT)
{
  __shared__ float t[32][33];
  const int b = blockIdx.x;
  if (b < 10240) {
    const float* in; unsigned short* out; int i;
    if (b < 8192)      { in = x;  out = xb;  i = b * 256 + threadIdx.x; }
    else if (b < 9216) { in = wq; out = wqb; i = (b - 8192) * 256 + threadIdx.x; }
    else               { in = wk; out = wkb; i = (b - 9216) * 256 + threadIdx.x; }
    const float4 f = ((const float4*)in)[i];
    us4 v;
    v[0] = f2bf(f.x); v[1] = f2bf(f.y); v[2] = f2bf(f.z); v[3] = f2bf(f.w);
    ((us4*)out)[i] = v;
  } else {
    const float* in = (b < 11264) ? wv : wo;
    unsigned short* out = (b < 11264) ? vtb : opT;
    const int tb = (b < 11264) ? (b - 10240) : (b - 11264);
    const int bx = (tb & 31) * 32, by = (tb >> 5) * 32;
    const int tx = threadIdx.x & 31, ty = threadIdx.x >> 5;
#pragma unroll
    for (int i = 0; i < 32; i += 8)
      t[ty + i][tx] = in[(size_t)(by + ty + i) * 1024 + bx + tx];
    __syncthreads();
#pragma unroll
    for (int i = 0; i < 32; i += 8)
      out[(size_t)(bx + ty + i) * 1024 + by + tx] = f2bf(t[tx][ty + i]);
  }
}

// ============ 256x256 8-phase K-loop (BK=64, 512 thr / 8 waves) =============
// Wave grid 2M x 4N; wave tile 128x64 (m rows: mh*128 + wm*64 + i*16;
// n cols: nh*128 + wn*32 + j*16). LDS: 2 K-tile buffers (stride 64 KiB):
//   A half0 @ +0, A half1 @ +16K, B half0 @ +32K, B half1 @ +48K  (each 128x64 bf16)
// XOR swizzle byte ^= (row&7)<<4 applied via inverse-swizzled global source
// (global_load_lds writes linearly) + same XOR on ds_read address.
// Per K-tile, 4 phases = C-quadrants (0,0),(0,1),(1,1),(1,0); each phase:
//   { ds_read quadrant frags; stage 1 half-tile (2x GL2LDS); barrier;
//     setprio(1); 16 MFMA; setprio(0); barrier }
// Stage ledger: p1:Ah1(t+1) p2:Bh0(t+1) p3:Ah0(t+2) p4:Bh1(t+2).
// Single counted wait per tile: vmcnt(4) at p4 end (retires through p2(t-1),
// leaving {p3,p4} of the current tile in flight); vmcnt(0) only at tail.
__device__ __forceinline__ void kloop256(
    const unsigned short* __restrict__ Abase,
    const unsigned short* __restrict__ Bbase,
    const int lda, const int ldw, const int NT,   // NT = K/64, NT >= 2
    char* smem, f32x4 (&acc)[8][4])
{
  const int tid = threadIdx.x;
  const int lane = tid & 63, wave = tid >> 6;
  const int quad = lane >> 4, l16 = lane & 15;
  const int wm = wave >> 2, wn = wave & 3;

  // read-side swizzled column offsets (bytes)
  const int c0 = (quad * 16) ^ ((l16 & 7) << 4);
  const int c1 = (64 + quad * 16) ^ ((l16 & 7) << 4);
  const int aRd = (wm * 64 + l16) * 128;            // byte row base in A half
  const int bRd = 32768 + (wn * 32 + l16) * 128;    // byte base in B (nh adds 16K)

  // stage-side: thread covers LDS row (tid>>3)+64*rnd, inverse-swizzled global col
  const int scol = ((tid & 7) ^ ((tid >> 3) & 7)) << 3;   // element offset
  const unsigned short* As0 = Abase + (size_t)(tid >> 3) * lda + scol;
  const unsigned short* Bs0 = Bbase + (size_t)(tid >> 3) * ldw + scol;

#define STAGE_A(buf, h, kt) do { \
    GL2LDS(As0 + (size_t)((h) * 128) * lda + (kt) * 64,      (buf) + (h) * 16384 +        tid * 16); \
    GL2LDS(As0 + (size_t)((h) * 128 + 64) * lda + (kt) * 64, (buf) + (h) * 16384 + 8192 + tid * 16); } while (0)
#define STAGE_B(buf, h, kt) do { \
    GL2LDS(Bs0 + (size_t)((h) * 128) * ldw + (kt) * 64,      (buf) + 32768 + (h) * 16384 +        tid * 16); \
    GL2LDS(Bs0 + (size_t)((h) * 128 + 64) * ldw + (kt) * 64, (buf) + 32768 + (h) * 16384 + 8192 + tid * 16); } while (0)
#define READ_A(mh) do { _Pragma("unroll") for (int i = 0; i < 4; ++i) { \
    af[i][0] = *(const bf16x8*)(cur + (mh) * 16384 + aRd + i * 2048 + c0); \
    af[i][1] = *(const bf16x8*)(cur + (mh) * 16384 + aRd + i * 2048 + c1); } } while (0)
#define READ_B(nh) do { _Pragma("unroll") for (int j = 0; j < 2; ++j) { \
    bf[j][0] = *(const bf16x8*)(cur + (nh) * 16384 + bRd + j * 2048 + c0); \
    bf[j][1] = *(const bf16x8*)(cur + (nh) * 16384 + bRd + j * 2048 + c1); } } while (0)
#define MFMA_Q(mh, nh) do { __builtin_amdgcn_s_setprio(1); \
    _Pragma("unroll") for (int i = 0; i < 4; ++i) \
    _Pragma("unroll") for (int j = 0; j < 2; ++j) \
    _Pragma("unroll") for (int ks = 0; ks < 2; ++ks) \
      acc[(mh) * 4 + i][(nh) * 2 + j] = __builtin_amdgcn_mfma_f32_16x16x32_bf16( \
          af[i][ks], bf[j][ks], acc[(mh) * 4 + i][(nh) * 2 + j], 0, 0, 0); \
    __builtin_amdgcn_s_setprio(0); } while (0)

  char* cur = smem;
  char* nxt = smem + 65536;

  // prologue: tile0 full; tile1 Ah0 + Bh1 (Ah1/Bh0 of tile1 staged in body t=0)
  STAGE_A(cur, 0, 0); STAGE_A(cur, 1, 0); STAGE_B(cur, 0, 0); STAGE_B(cur, 1, 0);
  STAGE_A(nxt, 0, 1); STAGE_B(nxt, 1, 1);
  asm volatile("s_waitcnt vmcnt(0)" ::: "memory");
  __builtin_amdgcn_s_barrier();

  for (int t = 0; t < NT; ++t) {
    bf16x8 af[4][2], bf[2][2];
    const bool s1 = (t + 1 < NT), s2 = (t + 2 < NT);

    // ---- p1: quadrant (0,0)
    READ_A(0); READ_B(0);
    if (s1) STAGE_A(nxt, 1, t + 1);
    BARRIER(); SCHED0();
    MFMA_Q(0, 0);
    BARRIER();
    // ---- p2: (0,1), reuse A frags
    READ_B(1);
    if (s1) STAGE_B(nxt, 0, t + 1);
    BARRIER(); SCHED0();
    MFMA_Q(0, 1);
    BARRIER();
    // ---- p3: (1,1), reuse B frags
    READ_A(1);
    if (s2) STAGE_A(cur, 0, t + 2);
    BARRIER(); SCHED0();
    MFMA_Q(1, 1);
    BARRIER();
    // ---- p4: (1,0)
    READ_B(0);
    if (s2) STAGE_B(cur, 1, t + 2);
    BARRIER(); SCHED0();
    MFMA_Q(1, 0);
    if (s2) { asm volatile("s_waitcnt vmcnt(4)" ::: "memory"); }
    else    { asm volatile("s_waitcnt vmcnt(0)" ::: "memory"); }
    __builtin_amdgcn_s_barrier();

    char* tp = cur; cur = nxt; nxt = tp;
  }
#undef STAGE_A
#undef STAGE_B
#undef READ_A
#undef READ_B
#undef MFMA_Q
}

// ---------------- epilogues ----------------
__device__ __forceinline__ void epi_bf16(const f32x4 (&acc)[8][4], unsigned short* __restrict__ C,
                                         int ldc, int m0, int n0, char* smem)
{
  const int tid = threadIdx.x, lane = tid & 63, wave = tid >> 6;
  const int quad = lane >> 4, l16 = lane & 15;
  const int wm = wave >> 2, wn = wave & 3;
  unsigned short* patch = (unsigned short*)smem + wave * (16 * 72);
#pragma unroll
  for (int mf = 0; mf < 8; ++mf) {
#pragma unroll
    for (int an = 0; an < 4; ++an)
#pragma unroll
      for (int r = 0; r < 4; ++r)
        patch[(quad * 4 + r) * 72 + an * 16 + l16] = f2bf(acc[mf][an][r]);
    __builtin_amdgcn_wave_barrier();
    const int grow0 = m0 + (mf >> 2) * 128 + wm * 64 + (mf & 3) * 16;
#pragma unroll
    for (int it = 0; it < 2; ++it) {
      const int rr = it * 8 + (lane >> 3);
      const int cp = (lane & 7) * 8;
      us8 v = *(const us8*)&patch[rr * 72 + cp];
      const int gcol = n0 + (cp >> 5) * 128 + wn * 32 + (cp & 31);
      *(us8*)&C[(size_t)(grow0 + rr) * ldc + gcol] = v;
    }
    __builtin_amdgcn_wave_barrier();
  }
}

__device__ __forceinline__ void epi_atomic(const f32x4 (&acc)[8][4], float* __restrict__ C,
                                           int ldc, int m0, int n0)
{
  const int lane = threadIdx.x & 63, wave = threadIdx.x >> 6;
  const int quad = lane >> 4, l16 = lane & 15;
  const int wm = wave >> 2, wn = wave & 3;
#pragma unroll
  for (int mf = 0; mf < 8; ++mf) {
    const int gr = m0 + (mf >> 2) * 128 + wm * 64 + (mf & 3) * 16 + quad * 4;
#pragma unroll
    for (int an = 0; an < 4; ++an) {
      const int gc = n0 + (an >> 1) * 128 + wn * 32 + (an & 1) * 16 + l16;
#pragma unroll
      for (int r = 0; r < 4; ++r)
        atomicAdd(&C[(size_t)(gr + r) * ldc + gc], acc[mf][an][r]);
    }
  }
}

// ---------------- fused QKV' projection (BM=BN=256) ----------------
// blockIdx.x in [0,12): wsel = x>>2, n0 = (x&3)*256.
// wsel 0: Q, 1: K, 2: V' = x @ Wct^T stored transposed VT[b][j][s].
__global__ __launch_bounds__(512, 2)
void gemm_qkv(const unsigned short* __restrict__ xb,
              const unsigned short* __restrict__ wq, const unsigned short* __restrict__ wk,
              const unsigned short* __restrict__ wct,
              unsigned short* __restrict__ Q, unsigned short* __restrict__ Kb,
              unsigned short* __restrict__ VT)
{
  const int m0 = blockIdx.y * 256;
  const int wsel = blockIdx.x >> 2;
  const int n0 = (blockIdx.x & 3) * 256;
  const unsigned short* W = (wsel == 0) ? wq : (wsel == 1) ? wk : wct;

  __shared__ __align__(16) char smem[131072];
  f32x4 acc[8][4] = {};
  kloop256(xb + (size_t)m0 * 1024, W + (size_t)n0 * 1024, 1024, 1024, 16, smem, acc);
  __syncthreads();

  const int lane = threadIdx.x & 63, wave = threadIdx.x >> 6;
  const int quad = lane >> 4, l16 = lane & 15;
  const int wm = wave >> 2, wn = wave & 3;
  if (wsel == 2) {
#pragma unroll
    for (int mf = 0; mf < 8; ++mf) {
      const int gr = m0 + (mf >> 2) * 128 + wm * 64 + (mf & 3) * 16 + quad * 4;
      const int b = gr >> 11, s = gr & 2047;
#pragma unroll
      for (int an = 0; an < 4; ++an) {
        const int gc = n0 + (an >> 1) * 128 + wn * 32 + (an & 1) * 16 + l16;
        us4 v;
#pragma unroll
        for (int r = 0; r < 4; ++r) v[r] = f2bf(acc[mf][an][r]);
        *(us4*)(VT + (size_t)b * (1024 * 2048) + (size_t)gc * 2048 + s) = v;
      }
    }
  } else {
    epi_bf16(acc, (wsel == 0) ? Q : Kb, 1024, m0, n0, smem);
  }
}

// ---------------- generic bf16 GEMM: C = A @ W^T (BM=BN=256) ----------------
// MODE 0: C bf16 store. MODE 2: C f32 atomicAdd (pre-zeroed).
// CAUSAL: block skip. PVSPLIT: z = batch*2+half, Keff = m0+256 split in 2.
template<int MODE, bool CAUSAL, bool PVSPLIT>
__global__ __launch_bounds__(512, 2)
void gemm_bt(const unsigned short* __restrict__ A, const unsigned short* __restrict__ W,
             void* __restrict__ Cv, int lda, int ldw, int ldc, int K,
             long long sAz, long long sWz, long long sCz)
{
  const int m0 = blockIdx.y * 256;
  const int n0 = blockIdx.x * 256;
  if (CAUSAL && n0 > m0 + 255) return;
  int z = blockIdx.z, kb = 0, Keff = K;
  if (PVSPLIT) {
    const int h = z & 1; z >>= 1;
    const int kfull = m0 + 256;
    kb = h * (kfull >> 1);
    Keff = kfull >> 1;
  }

  __shared__ __align__(16) char smem[131072];
  f32x4 acc[8][4] = {};
  kloop256(A + (size_t)z * sAz + (size_t)m0 * lda + kb,
           W + (size_t)z * sWz + (size_t)n0 * ldw + kb,
           lda, ldw, Keff >> 6, smem, acc);
  __syncthreads();

  if (MODE == 0)
    epi_bf16(acc, (unsigned short*)Cv + (size_t)z * sCz, ldc, m0, n0, smem);
  else
    epi_atomic(acc, (float*)Cv + (size_t)z * sCz, ldc, m0, n0);
}

// causal softmax; blockIdx.x = b*2048 + r; valid cols [0,r]; scale 1/32 pre-exp.
// Zero-fills out to the 256-aligned band [0, ((r>>8)+1)*256) that BM=256 PV reads.
__global__ __launch_bounds__(256)
void softmax_causal(unsigned short* __restrict__ SP)
{
  const int gid = blockIdx.x;
  const int r   = gid & 2047;
  const int tid = threadIdx.x;
  unsigned short* row = SP + (size_t)gid * 2048;
  const int n  = r + 1;
  const int it = (r >> 8) + 1;   // active 256-col chunks

  float vals[8];
  float lmax = -1e30f;
#pragma unroll
  for (int i = 0; i < 8; ++i) {
    const int c = tid + i * 256;
    if (i < it) {
      const float f = bf2f(row[c]);
      vals[i] = f;
      if (c < n) lmax = fmaxf(lmax, f);
    }
  }
#pragma unroll
  for (int m = 32; m; m >>= 1) lmax = fmaxf(lmax, __shfl_xor(lmax, m, 64));
  __shared__ float redm[4], reds[4];
  if ((tid & 63) == 0) redm[tid >> 6] = lmax;
  __syncthreads();
  lmax = fmaxf(fmaxf(redm[0], redm[1]), fmaxf(redm[2], redm[3]));

  float e[8];
  float lsum = 0.f;
#pragma unroll
  for (int i = 0; i < 8; ++i) {
    const int c = tid + i * 256;
    const float ev = (c < n) ? __expf((vals[i] - lmax) * 0.03125f) : 0.f;
    e[i] = ev;
    lsum += ev;
  }
#pragma unroll
  for (int m = 32; m; m >>= 1) lsum += __shfl_xor(lsum, m, 64);
  if ((tid & 63) == 0) reds[tid >> 6] = lsum;
  __syncthreads();
  lsum = reds[0] + reds[1] + reds[2] + reds[3];
  const float inv = 1.f / lsum;
#pragma unroll
  for (int i = 0; i < 8; ++i) {
    const int c = tid + i * 256;
    if (i < it) row[c] = f2bf(e[i] * inv);
  }
}

extern "C" void kernel_launch(void* const* d_in, const int* in_sizes, int n_in,
                              void* d_out, int out_size, void* d_ws, size_t ws_size,
                              hipStream_t stream)
{
  (void)in_sizes; (void)n_in; (void)ws_size;
  // dict order: k, q, v, out_proj, x — f32 inputs, f32 output
  const float* wk_f = (const float*)d_in[0];
  const float* wq_f = (const float*)d_in[1];
  const float* wv_f = (const float*)d_in[2];
  const float* wo_f = (const float*)d_in[3];
  const float* x_f  = (const float*)d_in[4];
  float* out = (float*)d_out;

  // ws layout (98 MiB):
  char* p = (char*)d_ws;
  unsigned short* xb   = (unsigned short*)(p);                       // [0,16M)
  unsigned short* Q    = (unsigned short*)(p + ((size_t)16 << 20));  // [16,32M)
  unsigned short* Kb   = (unsigned short*)(p + ((size_t)32 << 20));  // [32,48M)
  unsigned short* VT   = (unsigned short*)(p + ((size_t)48 << 20));  // [48,64M): V'^T [B][j][s]
  unsigned short* SP   = (unsigned short*)(p + ((size_t)64 << 20));  // [64,96M): [B][S][S]
  unsigned short* wqb  = (unsigned short*)(p + ((size_t)64 << 20));  // aliases (dead before scores)
  unsigned short* wkb  = (unsigned short*)(p + ((size_t)66 << 20));
  unsigned short* vtb  = (unsigned short*)(p + ((size_t)68 << 20));  // v^T bf16
  unsigned short* wctb = (unsigned short*)(p + ((size_t)70 << 20));  // Wct = (v^T@out_proj)^T
  unsigned short* opT  = (unsigned short*)(p + ((size_t)96 << 20));  // [96,98M)

  dim3 blk256(256), blk512(512);

  // zero d_out for PV split-K atomic accumulation
  hipMemsetAsync(d_out, 0, (size_t)out_size, stream);

  // conversions + transposes (x, wq, wk, v^T, out_proj^T)
  prep<<<dim3(12288), blk256, 0, stream>>>(x_f, wq_f, wk_f, wv_f, wo_f, xb, wqb, wkb, vtb, opT);

  // Wct[j][e] = sum_d out_proj[d][j] * v[d][e], tiny GEMM (1024^3)
  gemm_bt<0, false, false><<<dim3(4, 4, 1), blk512, 0, stream>>>(opT, vtb, wctb,
      1024, 1024, 1024, 1024, 0, 0, 0);

  // fused Q/K/V' projections: M=8192, N=3*1024, K=1024
  gemm_qkv<<<dim3(12, 32), blk512, 0, stream>>>(xb, wqb, wkb, wctb, Q, Kb, VT);

  // scores (all batches): [B][2048,2048] = Q @ K^T, causal block skip
  gemm_bt<0, true, false><<<dim3(8, 8, 4), blk512, 0, stream>>>(Q, Kb, SP,
      1024, 1024, 2048, 1024,
      (long long)2048 * 1024, (long long)2048 * 1024, (long long)2048 * 2048);

  // P = causal_softmax(scores/32), in place, all batches
  softmax_causal<<<dim3(8192), blk256, 0, stream>>>(SP);

  // out = P @ V', K split in 2 per m-tile (z = batch*2 + half), f32 atomicAdd
  gemm_bt<2, false, true><<<dim3(4, 8, 8), blk512, 0, stream>>>(SP, VT, out,
      2048, 2048, 1024, 2048,
      (long long)2048 * 2048, (long long)1024 * 2048, (long long)2048 * 1024);
}

// Round 3
// 284.809 us; speedup vs baseline: 1.0884x; 1.0884x over previous
//
#include <hip/hip_runtime.h>
#include <stdint.h>

typedef __attribute__((ext_vector_type(8))) short bf16x8;   // 8 bf16 = 4 VGPR (MFMA A/B frag)
typedef __attribute__((ext_vector_type(4))) float f32x4;    // MFMA C/D frag
typedef __attribute__((ext_vector_type(4))) unsigned short us4;
typedef __attribute__((ext_vector_type(8))) unsigned short us8;

__device__ __forceinline__ unsigned short f2bf(float f) {   // RNE f32 -> bf16
  union { float f; unsigned u; } x; x.f = f;
  unsigned r = x.u + 0x7FFFu + ((x.u >> 16) & 1u);
  return (unsigned short)(r >> 16);
}
__device__ __forceinline__ float bf2f(unsigned short h) {
  union { unsigned u; float f; } x; x.u = ((unsigned)h) << 16;
  return x.f;
}

// async global->LDS, 16B per lane; LDS dest is wave-uniform base + lane*16
#define GL2LDS(g, l) __builtin_amdgcn_global_load_lds( \
    (const __attribute__((address_space(1))) unsigned int*)(g), \
    (__attribute__((address_space(3))) unsigned int*)(l), 16, 0, 0)

// raw barrier with compiler memory fence (no vmcnt/lgkm drain at runtime)
#define BARRIER() do { asm volatile("" ::: "memory"); \
  __builtin_amdgcn_s_barrier(); asm volatile("" ::: "memory"); } while (0)
#define SCHED0() __builtin_amdgcn_sched_barrier(0)

// ---------------- fused prep (unchanged) ----------------
__global__ __launch_bounds__(256)
void prep(const float* __restrict__ x,
          const float* __restrict__ wq, const float* __restrict__ wk,
          const float* __restrict__ wv, const float* __restrict__ wo,
          unsigned short* __restrict__ xb,
          unsigned short* __restrict__ wqb, unsigned short* __restrict__ wkb,
          unsigned short* __restrict__ vtb, unsigned short* __restrict__ opT)
{
  __shared__ float t[32][33];
  const int b = blockIdx.x;
  if (b < 10240) {
    const float* in; unsigned short* out; int i;
    if (b < 8192)      { in = x;  out = xb;  i = b * 256 + threadIdx.x; }
    else if (b < 9216) { in = wq; out = wqb; i = (b - 8192) * 256 + threadIdx.x; }
    else               { in = wk; out = wkb; i = (b - 9216) * 256 + threadIdx.x; }
    const float4 f = ((const float4*)in)[i];
    us4 v;
    v[0] = f2bf(f.x); v[1] = f2bf(f.y); v[2] = f2bf(f.z); v[3] = f2bf(f.w);
    ((us4*)out)[i] = v;
  } else {
    const float* in = (b < 11264) ? wv : wo;
    unsigned short* out = (b < 11264) ? vtb : opT;
    const int tb = (b < 11264) ? (b - 10240) : (b - 11264);
    const int bx = (tb & 31) * 32, by = (tb >> 5) * 32;
    const int tx = threadIdx.x & 31, ty = threadIdx.x >> 5;
#pragma unroll
    for (int i = 0; i < 32; i += 8)
      t[ty + i][tx] = in[(size_t)(by + ty + i) * 1024 + bx + tx];
    __syncthreads();
#pragma unroll
    for (int i = 0; i < 32; i += 8)
      out[(size_t)(bx + ty + i) * 1024 + by + tx] = f2bf(t[tx][ty + i]);
  }
}

// ============ 128x256 8-phase K-loop (BK=64, 512 thr / 8 waves) =============
// Wave grid 1x8: wave-tile 128x32 (all 128 rows, cols wn*32).
// LDS: 3 K-tile buffers (stride 48 KiB): A [128][64] @ +0 (16K),
// Bh0 [128][64] @ +16K, Bh1 @ +32K. Rows 128B; XOR swizzle byte^=(row&7)<<4
// applied via inverse-swizzled global source + same XOR on ds_read address.
// 4 phases per K-tile: p1 {rd A0-3,B an0; stage A(t+2)}, p2 {rd A4-7; stage
// Bh0(t+2)}, p3 {rd B an1; stage Bh1(t+2)}, p4 {}; each phase = barrier,
// 8 MFMA under setprio, barrier. Single counted wait per tile: vmcnt(6) at
// p4 end retires tile(t+1)'s 6 loads (issued during t-1 => ~6 phases of
// latency slack, > HBM ~900cy); vmcnt(0) only in the tail.
__device__ __forceinline__ void kloop128(
    const unsigned short* __restrict__ Abase,
    const unsigned short* __restrict__ Bbase,
    const int lda, const int ldw, const int NT,   // NT = K/64, NT >= 2
    char* smem, f32x4 (&acc)[8][2])
{
  const int tid = threadIdx.x;
  const int lane = tid & 63, wave = tid >> 6;
  const int quad = lane >> 4, l16 = lane & 15;
  const int wn = wave;

  // read-side swizzled column offsets (bytes)
  const int c0 = (quad * 16) ^ ((l16 & 7) << 4);
  const int c1 = (64 + quad * 16) ^ ((l16 & 7) << 4);
  const int aRd = l16 * 128;                                          // + mf*2048
  const int bRd = 16384 + (wn >> 2) * 16384 + ((wn & 3) * 32 + l16) * 128;  // + an*2048

  // stage-side: thread covers LDS row (tid>>3), inverse-swizzled global col
  const int scol = ((tid & 7) ^ ((tid >> 3) & 7)) << 3;   // element offset
  const unsigned short* As0 = Abase + (size_t)(tid >> 3) * lda + scol;
  const unsigned short* Bs0 = Bbase + (size_t)(tid >> 3) * ldw + scol;

#define STAGE_A(buf, kt) do { \
    GL2LDS(As0 + (kt) * 64,                     (buf) +        tid * 16); \
    GL2LDS(As0 + (size_t)64 * lda + (kt) * 64,  (buf) + 8192 + tid * 16); } while (0)
#define STAGE_B(buf, h, kt) do { \
    GL2LDS(Bs0 + (size_t)((h) * 128) * ldw + (kt) * 64,      (buf) + 16384 + (h) * 16384 +        tid * 16); \
    GL2LDS(Bs0 + (size_t)((h) * 128 + 64) * ldw + (kt) * 64, (buf) + 16384 + (h) * 16384 + 8192 + tid * 16); } while (0)
#define READ_A(half) do { _Pragma("unroll") for (int i = 0; i < 4; ++i) { \
    af[(half) * 4 + i][0] = *(const bf16x8*)(cur + aRd + ((half) * 4 + i) * 2048 + c0); \
    af[(half) * 4 + i][1] = *(const bf16x8*)(cur + aRd + ((half) * 4 + i) * 2048 + c1); } } while (0)
#define READ_B(an) do { \
    bfr[an][0] = *(const bf16x8*)(cur + bRd + (an) * 2048 + c0); \
    bfr[an][1] = *(const bf16x8*)(cur + bRd + (an) * 2048 + c1); } while (0)
#define MFMA_P(half, an) do { __builtin_amdgcn_s_setprio(1); \
    _Pragma("unroll") for (int i = 0; i < 4; ++i) \
    _Pragma("unroll") for (int ks = 0; ks < 2; ++ks) \
      acc[(half) * 4 + i][an] = __builtin_amdgcn_mfma_f32_16x16x32_bf16( \
          af[(half) * 4 + i][ks], bfr[an][ks], acc[(half) * 4 + i][an], 0, 0, 0); \
    __builtin_amdgcn_s_setprio(0); } while (0)

  char* b0 = smem;
  char* b1 = smem + 49152;
  char* b2 = smem + 98304;

  // prologue: stage tiles 0 and 1 (6 loads each)
  STAGE_A(b0, 0); STAGE_B(b0, 0, 0); STAGE_B(b0, 1, 0);
  STAGE_A(b1, 1); STAGE_B(b1, 0, 1); STAGE_B(b1, 1, 1);
  asm volatile("s_waitcnt vmcnt(6)" ::: "memory");   // tile0 landed; tile1 in flight
  __builtin_amdgcn_s_barrier();

  for (int t = 0; t < NT; ++t) {
    char* cur = b0;
    bf16x8 af[8][2], bfr[2][2];
    const bool s2 = (t + 2 < NT);

    // ---- p1
    READ_A(0); READ_B(0);
    if (s2) STAGE_A(b2, t + 2);
    BARRIER(); SCHED0();
    MFMA_P(0, 0);
    BARRIER();
    // ---- p2
    READ_A(1);
    if (s2) STAGE_B(b2, 0, t + 2);
    BARRIER(); SCHED0();
    MFMA_P(1, 0);
    BARRIER();
    // ---- p3
    READ_B(1);
    if (s2) STAGE_B(b2, 1, t + 2);
    BARRIER(); SCHED0();
    MFMA_P(0, 1);
    BARRIER();
    // ---- p4
    SCHED0();
    MFMA_P(1, 1);
    if (s2) { asm volatile("s_waitcnt vmcnt(6)" ::: "memory"); }
    else    { asm volatile("s_waitcnt vmcnt(0)" ::: "memory"); }
    __builtin_amdgcn_s_barrier();

    char* tp = b0; b0 = b1; b1 = b2; b2 = tp;
  }
#undef STAGE_A
#undef STAGE_B
#undef READ_A
#undef READ_B
#undef MFMA_P
}

// ---------------- epilogues (wave-tile 128x32) ----------------
__device__ __forceinline__ void epi_bf16(const f32x4 (&acc)[8][2], unsigned short* __restrict__ C,
                                         int ldc, int m0, int n0, char* smem)
{
  const int tid = threadIdx.x, lane = tid & 63, wave = tid >> 6;
  const int quad = lane >> 4, l16 = lane & 15;
  unsigned short* patch = (unsigned short*)smem + wave * (16 * 40);
  const int gc0 = n0 + wave * 32;
#pragma unroll
  for (int mf = 0; mf < 8; ++mf) {
#pragma unroll
    for (int an = 0; an < 2; ++an)
#pragma unroll
      for (int r = 0; r < 4; ++r)
        patch[(quad * 4 + r) * 40 + an * 16 + l16] = f2bf(acc[mf][an][r]);
    __builtin_amdgcn_wave_barrier();
    const int row = lane >> 2, seg = lane & 3;
    us8 v = *(const us8*)&patch[row * 40 + seg * 8];
    *(us8*)&C[(size_t)(m0 + mf * 16 + row) * ldc + gc0 + seg * 8] = v;
    __builtin_amdgcn_wave_barrier();
  }
}

__device__ __forceinline__ void epi_f32(const f32x4 (&acc)[8][2], float* __restrict__ C,
                                        int ldc, int m0, int n0, char* smem)
{
  const int tid = threadIdx.x, lane = tid & 63, wave = tid >> 6;
  const int quad = lane >> 4, l16 = lane & 15;
  float* patch = (float*)smem + wave * (16 * 36);
  const int gc0 = n0 + wave * 32;
#pragma unroll
  for (int mf = 0; mf < 8; ++mf) {
#pragma unroll
    for (int an = 0; an < 2; ++an)
#pragma unroll
      for (int r = 0; r < 4; ++r)
        patch[(quad * 4 + r) * 36 + an * 16 + l16] = acc[mf][an][r];
    __builtin_amdgcn_wave_barrier();
#pragma unroll
    for (int j = 0; j < 2; ++j) {
      const int row = j * 8 + (lane >> 3), seg = lane & 7;
      float4 v = *(const float4*)&patch[row * 36 + seg * 4];
      *(float4*)&C[(size_t)(m0 + mf * 16 + row) * ldc + gc0 + seg * 4] = v;
    }
    __builtin_amdgcn_wave_barrier();
  }
}

// ---------------- fused QKV' projection (BM=128, BN=256) ----------------
// blockIdx.x in [0,12): wsel = x>>2, n0 = (x&3)*256.
// wsel 0: Q, 1: K, 2: V' = x @ Wct^T stored transposed VT[b][j][s].
__global__ __launch_bounds__(512, 2)
void gemm_qkv(const unsigned short* __restrict__ xb,
              const unsigned short* __restrict__ wq, const unsigned short* __restrict__ wk,
              const unsigned short* __restrict__ wct,
              unsigned short* __restrict__ Q, unsigned short* __restrict__ Kb,
              unsigned short* __restrict__ VT)
{
  const int m0 = blockIdx.y * 128;
  const int wsel = blockIdx.x >> 2;
  const int n0 = (blockIdx.x & 3) * 256;
  const unsigned short* W = (wsel == 0) ? wq : (wsel == 1) ? wk : wct;

  __shared__ __align__(16) char smem[147456];
  f32x4 acc[8][2] = {};
  kloop128(xb + (size_t)m0 * 1024, W + (size_t)n0 * 1024, 1024, 1024, 16, smem, acc);
  __syncthreads();

  const int lane = threadIdx.x & 63, wave = threadIdx.x >> 6;
  const int quad = lane >> 4, l16 = lane & 15;
  if (wsel == 2) {
#pragma unroll
    for (int mf = 0; mf < 8; ++mf) {
      const int gr = m0 + mf * 16 + quad * 4;
      const int b = gr >> 11, s = gr & 2047;
#pragma unroll
      for (int an = 0; an < 2; ++an) {
        const int gc = n0 + wave * 32 + an * 16 + l16;
        us4 v;
#pragma unroll
        for (int r = 0; r < 4; ++r) v[r] = f2bf(acc[mf][an][r]);
        *(us4*)(VT + (size_t)b * (1024 * 2048) + (size_t)gc * 2048 + s) = v;
      }
    }
  } else {
    epi_bf16(acc, (wsel == 0) ? Q : Kb, 1024, m0, n0, smem);
  }
}

// ---------------- generic bf16 GEMM: C = A @ W^T (BM=128, BN=256) -----------
// MODE 0: C bf16 store. MODE 1: C f32 store.
// CAUSAL: block skip (n0 > m0+127). PVLIM: Keff = m0+128.
template<int MODE, bool CAUSAL, bool PVLIM>
__global__ __launch_bounds__(512, 2)
void gemm_bt(const unsigned short* __restrict__ A, const unsigned short* __restrict__ W,
             void* __restrict__ Cv, int lda, int ldw, int ldc, int K,
             long long sAz, long long sWz, long long sCz)
{
  const int m0 = blockIdx.y * 128;
  const int n0 = blockIdx.x * 256;
  if (CAUSAL && n0 > m0 + 127) return;
  const int z = blockIdx.z;

  __shared__ __align__(16) char smem[147456];
  f32x4 acc[8][2] = {};
  const int Keff = PVLIM ? (m0 + 128) : K;
  kloop128(A + (size_t)z * sAz + (size_t)m0 * lda,
           W + (size_t)z * sWz + (size_t)n0 * ldw,
           lda, ldw, Keff >> 6, smem, acc);
  __syncthreads();

  if (MODE == 0)
    epi_bf16(acc, (unsigned short*)Cv + (size_t)z * sCz, ldc, m0, n0, smem);
  else
    epi_f32(acc, (float*)Cv + (size_t)z * sCz, ldc, m0, n0, smem);
}

// ---------------- small 128x128 GEMM (4 waves, BK=32) for Wct ----------------
__global__ __launch_bounds__(256, 4)
void gemm_small(const unsigned short* __restrict__ A, const unsigned short* __restrict__ W,
                unsigned short* __restrict__ C)
{
  const int m0 = blockIdx.y * 128;
  const int n0 = blockIdx.x * 128;
  const int tid = threadIdx.x;
  const int lane = tid & 63, wave = tid >> 6;
  const int quad = lane >> 4, l16 = lane & 15;
  const int wm = wave & 1, wn = wave >> 1;

  __shared__ __align__(16) char smem[16384];
  char* ldsA = smem; char* ldsW = smem + 8192;
  const int wrow = tid >> 2;
  const unsigned short* Ab = A + (size_t)m0 * 1024 + (tid & 3) * 8;
  const unsigned short* Wb = W + (size_t)n0 * 1024 + (tid & 3) * 8;

  f32x4 acc[4][4] = {};
  for (int k0 = 0; k0 < 1024; k0 += 32) {
    __syncthreads();
    GL2LDS(Ab + (size_t)wrow * 1024 + k0,        ldsA +        tid * 16);
    GL2LDS(Ab + (size_t)(wrow + 64) * 1024 + k0, ldsA + 4096 + tid * 16);
    GL2LDS(Wb + (size_t)wrow * 1024 + k0,        ldsW +        tid * 16);
    GL2LDS(Wb + (size_t)(wrow + 64) * 1024 + k0, ldsW + 4096 + tid * 16);
    __syncthreads();
    bf16x8 af[4], wf[4];
#pragma unroll
    for (int mt = 0; mt < 4; ++mt)
      af[mt] = *(const bf16x8*)(ldsA + ((wm * 64 + mt * 16 + l16) * 32 + quad * 8) * 2);
#pragma unroll
    for (int nt = 0; nt < 4; ++nt)
      wf[nt] = *(const bf16x8*)(ldsW + ((wn * 64 + nt * 16 + l16) * 32 + quad * 8) * 2);
#pragma unroll
    for (int mt = 0; mt < 4; ++mt)
#pragma unroll
      for (int nt = 0; nt < 4; ++nt)
        acc[mt][nt] = __builtin_amdgcn_mfma_f32_16x16x32_bf16(af[mt], wf[nt], acc[mt][nt], 0, 0, 0);
  }

  __syncthreads();
  const int gr0 = m0 + wm * 64;
  const int gc0 = n0 + wn * 64;
  unsigned short* patch = (unsigned short*)smem + wave * (16 * 72);
#pragma unroll
  for (int mt = 0; mt < 4; ++mt) {
#pragma unroll
    for (int nt = 0; nt < 4; ++nt)
#pragma unroll
      for (int r = 0; r < 4; ++r)
        patch[(quad * 4 + r) * 72 + nt * 16 + l16] = f2bf(acc[mt][nt][r]);
    __builtin_amdgcn_wave_barrier();
#pragma unroll
    for (int j = 0; j < 2; ++j) {
      const int rr = j * 8 + (lane >> 3);
      us8 v = *(const us8*)&patch[rr * 72 + (lane & 7) * 8];
      *(us8*)&C[(size_t)(gr0 + mt * 16 + rr) * 1024 + gc0 + (lane & 7) * 8] = v;
    }
    __builtin_amdgcn_wave_barrier();
  }
}

// causal softmax; blockIdx.x = b*2048 + r; valid cols [0,r]; scale 1/32 pre-exp.
// Touches only cols [0, ((r>>7)+1)*128) — exactly the band the PVLIM GEMM consumes.
__global__ __launch_bounds__(256)
void softmax_causal(unsigned short* __restrict__ SP)
{
  const int gid = blockIdx.x;
  const int r   = gid & 2047;
  const int tid = threadIdx.x;
  unsigned short* row = SP + (size_t)gid * 2048;
  const int n  = r + 1;
  const int nb = ((r >> 7) + 1) << 7;
  const int it = nb >> 8;
  const int rem = nb & 255;

  float vals[8];
  float lmax = -1e30f;
#pragma unroll
  for (int i = 0; i < 8; ++i) {
    const int c = tid + i * 256;
    if (i < it || (i == it && tid < rem)) {
      const float f = bf2f(row[c]);
      vals[i] = f;
      if (c < n) lmax = fmaxf(lmax, f);
    }
  }
#pragma unroll
  for (int m = 32; m; m >>= 1) lmax = fmaxf(lmax, __shfl_xor(lmax, m, 64));
  __shared__ float redm[4], reds[4];
  if ((tid & 63) == 0) redm[tid >> 6] = lmax;
  __syncthreads();
  lmax = fmaxf(fmaxf(redm[0], redm[1]), fmaxf(redm[2], redm[3]));

  float e[8];
  float lsum = 0.f;
#pragma unroll
  for (int i = 0; i < 8; ++i) {
    const int c = tid + i * 256;
    const float ev = (c < n) ? __expf((vals[i] - lmax) * 0.03125f) : 0.f;
    e[i] = ev;
    lsum += ev;
  }
#pragma unroll
  for (int m = 32; m; m >>= 1) lsum += __shfl_xor(lsum, m, 64);
  if ((tid & 63) == 0) reds[tid >> 6] = lsum;
  __syncthreads();
  lsum = reds[0] + reds[1] + reds[2] + reds[3];
  const float inv = 1.f / lsum;
#pragma unroll
  for (int i = 0; i < 8; ++i) {
    const int c = tid + i * 256;
    if (i < it || (i == it && tid < rem))
      row[c] = f2bf(e[i] * inv);
  }
}

extern "C" void kernel_launch(void* const* d_in, const int* in_sizes, int n_in,
                              void* d_out, int out_size, void* d_ws, size_t ws_size,
                              hipStream_t stream)
{
  (void)in_sizes; (void)n_in; (void)out_size; (void)ws_size;
  // dict order: k, q, v, out_proj, x — f32 inputs, f32 output
  const float* wk_f = (const float*)d_in[0];
  const float* wq_f = (const float*)d_in[1];
  const float* wv_f = (const float*)d_in[2];
  const float* wo_f = (const float*)d_in[3];
  const float* x_f  = (const float*)d_in[4];
  float* out = (float*)d_out;

  // ws layout (98 MiB):
  char* p = (char*)d_ws;
  unsigned short* xb   = (unsigned short*)(p);                       // [0,16M)
  unsigned short* Q    = (unsigned short*)(p + ((size_t)16 << 20));  // [16,32M)
  unsigned short* Kb   = (unsigned short*)(p + ((size_t)32 << 20));  // [32,48M)
  unsigned short* VT   = (unsigned short*)(p + ((size_t)48 << 20));  // [48,64M): V'^T [B][j][s]
  unsigned short* SP   = (unsigned short*)(p + ((size_t)64 << 20));  // [64,96M): [B][S][S]
  unsigned short* wqb  = (unsigned short*)(p + ((size_t)64 << 20));  // aliases (dead before scores)
  unsigned short* wkb  = (unsigned short*)(p + ((size_t)66 << 20));
  unsigned short* vtb  = (unsigned short*)(p + ((size_t)68 << 20));  // v^T bf16
  unsigned short* wctb = (unsigned short*)(p + ((size_t)70 << 20));  // Wct = (v^T@out_proj)^T
  unsigned short* opT  = (unsigned short*)(p + ((size_t)96 << 20));  // [96,98M)

  dim3 blk256(256), blk512(512);

  // conversions + transposes (x, wq, wk, v^T, out_proj^T)
  prep<<<dim3(12288), blk256, 0, stream>>>(x_f, wq_f, wk_f, wv_f, wo_f, xb, wqb, wkb, vtb, opT);

  // Wct[j][e] = sum_d out_proj[d][j] * v[d][e], tiny GEMM (1024^3) on light tiles
  gemm_small<<<dim3(8, 8), blk256, 0, stream>>>(opT, vtb, wctb);

  // fused Q/K/V' projections: M=8192, N=3*1024, K=1024 — 768 blocks = 3 exact rounds
  gemm_qkv<<<dim3(12, 64), blk512, 0, stream>>>(xb, wqb, wkb, wctb, Q, Kb, VT);

  // scores (all batches): [B][2048,2048] = Q @ K^T, causal block skip
  gemm_bt<0, true, false><<<dim3(8, 16, 4), blk512, 0, stream>>>(Q, Kb, SP,
      1024, 1024, 2048, 1024,
      (long long)2048 * 1024, (long long)2048 * 1024, (long long)2048 * 2048);

  // P = causal_softmax(scores/32), in place, all batches
  softmax_causal<<<dim3(8192), blk256, 0, stream>>>(SP);

  // out = P @ V', K limited to diagonal band, f32 direct to d_out — 256 blocks
  gemm_bt<1, false, true><<<dim3(4, 16, 4), blk512, 0, stream>>>(SP, VT, out,
      2048, 2048, 1024, 2048,
      (long long)2048 * 2048, (long long)1024 * 2048, (long long)2048 * 1024);
}